// Round 1
// baseline (440.059 us; speedup 1.0000x reference)
//
#include <hip/hip_runtime.h>
#include <math.h>

#define B_N     16384
#define D_IN    784
#define D_HID   256
#define D_LAT   8
#define N_CTR   64
#define CH_N    64
#define N_CLS   10

#define DT_C    0.1f
#define EPS_C   1e-4f
#define PM_STEPS 4
#define TAU_C   0.9f
#define MGAIN   0.1f
#define EIG     0.06f
#define PLR_C   0.001f
#define T_STEPS 5

// ---------------- enc1: h1[B,256] = tanh(x @ W1 + b1) ----------------
// 64x64 tile, BK=16, 256 threads, 4x4 micro-tile. f32 vector-ALU GEMM.
__global__ __launch_bounds__(256) void enc1_kernel(
    const float* __restrict__ x, const float* __restrict__ W1,
    const float* __restrict__ b1, float* __restrict__ h1)
{
    __shared__ alignas(16) float As[16][68];   // [k][m], pad 68 -> 2-way write, clean b128 read
    __shared__ alignas(16) float Bs[16][64];   // [k][n]
    const int tid = threadIdx.x;
    const int n0 = blockIdx.x * 64;            // 0..3
    const int m0 = blockIdx.y * 64;            // 0..255
    const int tn = tid & 15, tm = tid >> 4;
    const int mload = tid >> 2, cload = tid & 3;
    const int kload = tid >> 4, nload4 = (tid & 15) * 4;

    float acc[4][4];
    #pragma unroll
    for (int i = 0; i < 4; ++i)
        #pragma unroll
        for (int j = 0; j < 4; ++j) acc[i][j] = 0.f;

    for (int kt = 0; kt < 49; ++kt) {
        const int k0 = kt * 16;
        float4 xv = *(const float4*)(x + (size_t)(m0 + mload) * D_IN + k0 + cload * 4);
        As[cload * 4 + 0][mload] = xv.x;
        As[cload * 4 + 1][mload] = xv.y;
        As[cload * 4 + 2][mload] = xv.z;
        As[cload * 4 + 3][mload] = xv.w;
        float4 wv = *(const float4*)(W1 + (size_t)(k0 + kload) * D_HID + n0 + nload4);
        *(float4*)&Bs[kload][nload4] = wv;
        __syncthreads();
        #pragma unroll
        for (int k = 0; k < 16; ++k) {
            float4 av = *(const float4*)&As[k][tm * 4];
            float4 bv = *(const float4*)&Bs[k][tn * 4];
            float a_[4] = {av.x, av.y, av.z, av.w};
            float b_[4] = {bv.x, bv.y, bv.z, bv.w};
            #pragma unroll
            for (int i = 0; i < 4; ++i)
                #pragma unroll
                for (int j = 0; j < 4; ++j)
                    acc[i][j] = fmaf(a_[i], b_[j], acc[i][j]);
        }
        __syncthreads();
    }
    #pragma unroll
    for (int i = 0; i < 4; ++i) {
        const int row = m0 + tm * 4 + i;
        float4 o;
        o.x = tanhf(acc[i][0] + b1[n0 + tn * 4 + 0]);
        o.y = tanhf(acc[i][1] + b1[n0 + tn * 4 + 1]);
        o.z = tanhf(acc[i][2] + b1[n0 + tn * 4 + 2]);
        o.w = tanhf(acc[i][3] + b1[n0 + tn * 4 + 3]);
        *(float4*)(h1 + (size_t)row * D_HID + n0 + tn * 4) = o;
    }
}

// ---------------- enc2: zT[d][b] = h1[b,:] @ W2[:,d] + b2[d] ----------------
__global__ __launch_bounds__(256) void enc2_kernel(
    const float* __restrict__ h1, const float* __restrict__ W2,
    const float* __restrict__ b2, float* __restrict__ zT)
{
    __shared__ alignas(16) float hs[32][260];
    __shared__ alignas(16) float w2t[8][260];
    const int tid = threadIdx.x;
    const int r0 = blockIdx.x * 32;
    for (int i = tid; i < D_HID * D_LAT; i += 256) {
        int k = i >> 3, d = i & 7;
        w2t[d][k] = W2[i];
    }
    #pragma unroll
    for (int i = 0; i < 8; ++i) {
        int idx = tid + i * 256;           // 0..2047
        int rr = idx >> 6, c4 = idx & 63;
        float4 v = *(const float4*)(h1 + (size_t)(r0 + rr) * D_HID + c4 * 4);
        *(float4*)&hs[rr][c4 * 4] = v;
    }
    __syncthreads();
    const int r = tid >> 3, d = tid & 7;
    float acc = 0.f;
    #pragma unroll 8
    for (int k4 = 0; k4 < 64; ++k4) {
        float4 a = *(const float4*)&hs[r][k4 * 4];
        float4 w = *(const float4*)&w2t[d][k4 * 4];
        acc = fmaf(a.x, w.x, acc);
        acc = fmaf(a.y, w.y, acc);
        acc = fmaf(a.z, w.z, acc);
        acc = fmaf(a.w, w.w, acc);
    }
    zT[(size_t)d * B_N + r0 + r] = acc + b2[d];
}

// ---------------- stepA: PM evolve + membrane + EI + act/post (+ outputs at last) ----------------
__global__ __launch_bounds__(64) void stepA_kernel(
    float* __restrict__ zT, float* __restrict__ hT,
    const float* __restrict__ mu, const float* __restrict__ c,
    const float* __restrict__ Wp, const float* __restrict__ bp,
    const float* __restrict__ Wr, const float* __restrict__ br,
    float* __restrict__ actT, float* __restrict__ postb,
    float* __restrict__ out, int t)
{
    __shared__ alignas(16) float mu_s[64];
    __shared__ alignas(16) float c_s[512];
    __shared__ alignas(16) float wp_s[512];
    __shared__ alignas(16) float bp_s[64];
    __shared__ alignas(16) float wr_s[640];
    __shared__ alignas(16) float br_s[16];
    const int tid = threadIdx.x;
    mu_s[tid] = mu[tid];
    bp_s[tid] = bp[tid];
    for (int i = tid; i < 512; i += 64) { c_s[i] = c[i]; wp_s[i] = Wp[i]; }
    const bool last = (t == T_STEPS - 1);
    if (last) {
        for (int i = tid; i < 640; i += 64) wr_s[i] = Wr[i];
        if (tid < N_CLS) br_s[tid] = br[tid];
    }
    __syncthreads();

    const int b = blockIdx.x * 64 + tid;
    float z[8];
    #pragma unroll
    for (int d = 0; d < 8; ++d) z[d] = zT[(size_t)d * B_N + b];

    // PM evolve: 4 substeps, full force sum before update
    #pragma unroll 1
    for (int it = 0; it < PM_STEPS; ++it) {
        float f[8];
        #pragma unroll
        for (int d = 0; d < 8; ++d) f[d] = 0.f;
        #pragma unroll 4
        for (int n = 0; n < N_CTR; ++n) {
            float dx[8];
            float r2 = EPS_C;
            #pragma unroll
            for (int d = 0; d < 8; ++d) {
                dx[d] = c_s[n * 8 + d] - z[d];
                r2 = fmaf(dx[d], dx[d], r2);
            }
            float w = mu_s[n] / r2;
            #pragma unroll
            for (int d = 0; d < 8; ++d) f[d] = fmaf(w, dx[d], f[d]);
        }
        #pragma unroll
        for (int d = 0; d < 8; ++d) z[d] = fmaf(DT_C, f[d], z[d]);
    }
    #pragma unroll
    for (int d = 0; d < 8; ++d) zT[(size_t)d * B_N + b] = z[d];

    // membrane + EI (hn kept fully unrolled in registers)
    float hn[CH_N];
    float s = 0.f;
    #pragma unroll
    for (int ch = 0; ch < CH_N; ++ch) {
        float a = bp_s[ch];
        #pragma unroll
        for (int d = 0; d < 8; ++d) a = fmaf(z[d], wp_s[d * 64 + ch], a);
        float hp = tanhf(a);
        float prev = (t == 0) ? 0.f : hT[(size_t)ch * B_N + b];
        float v = TAU_C * prev + MGAIN * hp;
        hn[ch] = v;
        s += v;
    }
    const float mean = s * (1.f / 64.f);
    float spost = 0.f;
    #pragma unroll
    for (int ch = 0; ch < CH_N; ++ch) {
        float hf = hn[ch] + EIG * (hn[ch] - mean);
        hn[ch] = hf;
        spost += hf;
        hT[(size_t)ch * B_N + b] = hf;
    }

    if (!last) {
        postb[b] = spost * (1.f / 64.f);
        #pragma unroll 4
        for (int n = 0; n < N_CTR; ++n) {
            float r2 = 0.f;
            #pragma unroll
            for (int d = 0; d < 8; ++d) {
                float dd = c_s[n * 8 + d] - z[d];
                r2 = fmaf(dd, dd, r2);
            }
            actT[(size_t)n * B_N + b] = expf(-r2);
        }
    } else {
        // logits (h_f @ Wr + br), z, h  -> d_out
        #pragma unroll 1
        for (int cls = 0; cls < N_CLS; ++cls) {
            float a = br_s[cls];
            #pragma unroll
            for (int ch = 0; ch < CH_N; ++ch) a = fmaf(hn[ch], wr_s[ch * 10 + cls], a);
            out[(size_t)b * 10 + cls] = a;
        }
        #pragma unroll
        for (int d = 0; d < 8; ++d) out[163840 + (size_t)b * 8 + d] = z[d];
        #pragma unroll
        for (int ch = 0; ch < CH_N; ++ch) out[294912 + (size_t)b * 64 + ch] = hn[ch];
    }
}

// ---------------- stepB: deterministic batch reduction -> mu', c' ----------------
__global__ __launch_bounds__(256) void stepB_kernel(
    const float* __restrict__ actT, const float* __restrict__ postb,
    const float* __restrict__ zT,
    const float* __restrict__ mu_in, const float* __restrict__ c_in,
    float* __restrict__ mu_out, float* __restrict__ c_out)
{
    const int n = blockIdx.x, tid = threadIdx.x;
    double a1 = 0.0, a2 = 0.0, a3[8];
    #pragma unroll
    for (int d = 0; d < 8; ++d) a3[d] = 0.0;
    const float* arow = actT + (size_t)n * B_N;
    for (int b = tid; b < B_N; b += 256) {
        float a = arow[b];
        a1 += (double)a;
        a2 += (double)a * (double)postb[b];
        #pragma unroll
        for (int d = 0; d < 8; ++d)
            a3[d] += (double)a * (double)zT[(size_t)d * B_N + b];
    }
    __shared__ double red[256][10];
    red[tid][0] = a1;
    red[tid][1] = a2;
    #pragma unroll
    for (int d = 0; d < 8; ++d) red[tid][2 + d] = a3[d];
    __syncthreads();
    for (int s = 128; s > 0; s >>= 1) {
        if (tid < s)
            for (int j = 0; j < 10; ++j) red[tid][j] += red[tid + s][j];
        __syncthreads();
    }
    if (tid == 0) {
        const float S1 = (float)red[0][0];
        const float S2 = (float)(red[0][1] * (1.0 / B_N));
        mu_out[n] = mu_in[n] + PLR_C * S2;
        const float denom = S1 + EPS_C;
        #pragma unroll
        for (int d = 0; d < 8; ++d) {
            float s3 = (float)red[0][2 + d];
            c_out[n * 8 + d] = c_in[n * 8 + d] + PLR_C * (s3 / denom - c_in[n * 8 + d] * (S1 / denom));
        }
    }
}

extern "C" void kernel_launch(void* const* d_in, const int* in_sizes, int n_in,
                              void* d_out, int out_size, void* d_ws, size_t ws_size,
                              hipStream_t stream) {
    (void)in_sizes; (void)n_in; (void)out_size; (void)ws_size;
    const float* x   = (const float*)d_in[0];
    const float* W1  = (const float*)d_in[1];
    const float* b1  = (const float*)d_in[2];
    const float* W2  = (const float*)d_in[3];
    const float* b2  = (const float*)d_in[4];
    const float* mu0 = (const float*)d_in[5];
    const float* c0  = (const float*)d_in[6];
    const float* Wp  = (const float*)d_in[7];
    const float* bp  = (const float*)d_in[8];
    const float* Wr  = (const float*)d_in[9];
    const float* br  = (const float*)d_in[10];
    float* out = (float*)d_out;
    float* ws  = (float*)d_ws;

    // ws layout (floats). h1 (16 MB) is dead after enc2; hT/actT/post alias it.
    float* h1    = ws;                       // [B,256]    4,194,304
    float* hT    = ws;                       // [64][B]    1,048,576 (aliases h1)
    float* actT  = ws + 1048576;             // [64][B]    1,048,576 (aliases h1)
    float* postb = ws + 2097152;             // [B]           16,384 (aliases h1)
    float* zT    = ws + 4194304;             // [8][B]       131,072
    float* mu_buf = ws + 4325376;            // 2 x 64
    float* c_buf  = ws + 4325504;            // 2 x 512

    enc1_kernel<<<dim3(4, 256), 256, 0, stream>>>(x, W1, b1, h1);
    enc2_kernel<<<512, 256, 0, stream>>>(h1, W2, b2, zT);

    const float* mu_cur = mu0;
    const float* c_cur  = c0;
    for (int t = 0; t < T_STEPS; ++t) {
        stepA_kernel<<<256, 64, 0, stream>>>(zT, hT, mu_cur, c_cur, Wp, bp, Wr, br,
                                             actT, postb, out, t);
        if (t < T_STEPS - 1) {
            float* mo = mu_buf + (t & 1) * 64;
            float* co = c_buf  + (t & 1) * 512;
            stepB_kernel<<<64, 256, 0, stream>>>(actT, postb, zT, mu_cur, c_cur, mo, co);
            mu_cur = mo;
            c_cur  = co;
        }
    }
}

// Round 2
// 200.004 us; speedup vs baseline: 2.2003x; 2.2003x over previous
//
#include <hip/hip_runtime.h>
#include <math.h>

#define B_N     16384
#define D_IN    784
#define D_HID   256
#define D_LAT   8
#define N_CTR   64
#define CH_N    64
#define N_CLS   10

#define DT_C    0.1f
#define EPS_C   1e-4f
#define PM_STEPS 4
#define TAU_C   0.9f
#define MGAIN   0.1f
#define EIG     0.06f
#define PLR_C   0.001f
#define T_STEPS 5

// ---------------- enc1: h1[B,256] = tanh(x @ W1 + b1) ---------------- (unchanged)
__global__ __launch_bounds__(256) void enc1_kernel(
    const float* __restrict__ x, const float* __restrict__ W1,
    const float* __restrict__ b1, float* __restrict__ h1)
{
    __shared__ alignas(16) float As[16][68];
    __shared__ alignas(16) float Bs[16][64];
    const int tid = threadIdx.x;
    const int n0 = blockIdx.x * 64;
    const int m0 = blockIdx.y * 64;
    const int tn = tid & 15, tm = tid >> 4;
    const int mload = tid >> 2, cload = tid & 3;
    const int kload = tid >> 4, nload4 = (tid & 15) * 4;

    float acc[4][4];
    #pragma unroll
    for (int i = 0; i < 4; ++i)
        #pragma unroll
        for (int j = 0; j < 4; ++j) acc[i][j] = 0.f;

    for (int kt = 0; kt < 49; ++kt) {
        const int k0 = kt * 16;
        float4 xv = *(const float4*)(x + (size_t)(m0 + mload) * D_IN + k0 + cload * 4);
        As[cload * 4 + 0][mload] = xv.x;
        As[cload * 4 + 1][mload] = xv.y;
        As[cload * 4 + 2][mload] = xv.z;
        As[cload * 4 + 3][mload] = xv.w;
        float4 wv = *(const float4*)(W1 + (size_t)(k0 + kload) * D_HID + n0 + nload4);
        *(float4*)&Bs[kload][nload4] = wv;
        __syncthreads();
        #pragma unroll
        for (int k = 0; k < 16; ++k) {
            float4 av = *(const float4*)&As[k][tm * 4];
            float4 bv = *(const float4*)&Bs[k][tn * 4];
            float a_[4] = {av.x, av.y, av.z, av.w};
            float b_[4] = {bv.x, bv.y, bv.z, bv.w};
            #pragma unroll
            for (int i = 0; i < 4; ++i)
                #pragma unroll
                for (int j = 0; j < 4; ++j)
                    acc[i][j] = fmaf(a_[i], b_[j], acc[i][j]);
        }
        __syncthreads();
    }
    #pragma unroll
    for (int i = 0; i < 4; ++i) {
        const int row = m0 + tm * 4 + i;
        float4 o;
        o.x = tanhf(acc[i][0] + b1[n0 + tn * 4 + 0]);
        o.y = tanhf(acc[i][1] + b1[n0 + tn * 4 + 1]);
        o.z = tanhf(acc[i][2] + b1[n0 + tn * 4 + 2]);
        o.w = tanhf(acc[i][3] + b1[n0 + tn * 4 + 3]);
        *(float4*)(h1 + (size_t)row * D_HID + n0 + tn * 4) = o;
    }
}

// ---------------- enc2: zT[b][d] = h1[b,:] @ W2[:,d] + b2[d] ----------------
__global__ __launch_bounds__(256) void enc2_kernel(
    const float* __restrict__ h1, const float* __restrict__ W2,
    const float* __restrict__ b2, float* __restrict__ zT)
{
    __shared__ alignas(16) float hs[32][260];
    __shared__ alignas(16) float w2t[8][260];
    const int tid = threadIdx.x;
    const int r0 = blockIdx.x * 32;
    for (int i = tid; i < D_HID * D_LAT; i += 256) {
        int k = i >> 3, d = i & 7;
        w2t[d][k] = W2[i];
    }
    #pragma unroll
    for (int i = 0; i < 8; ++i) {
        int idx = tid + i * 256;
        int rr = idx >> 6, c4 = idx & 63;
        float4 v = *(const float4*)(h1 + (size_t)(r0 + rr) * D_HID + c4 * 4);
        *(float4*)&hs[rr][c4 * 4] = v;
    }
    __syncthreads();
    const int r = tid >> 3, d = tid & 7;
    float acc = 0.f;
    #pragma unroll 8
    for (int k4 = 0; k4 < 64; ++k4) {
        float4 a = *(const float4*)&hs[r][k4 * 4];
        float4 w = *(const float4*)&w2t[d][k4 * 4];
        acc = fmaf(a.x, w.x, acc);
        acc = fmaf(a.y, w.y, acc);
        acc = fmaf(a.z, w.z, acc);
        acc = fmaf(a.w, w.w, acc);
    }
    zT[(size_t)(r0 + r) * 8 + d] = acc + b2[d];  // b-major layout
}

// ---------------- stepA2: 8 lanes per batch element ----------------
// lane sub=tid&7 handles centers {sub+8k} and channels {sub*8+j}.
__global__ __launch_bounds__(256) void stepA2_kernel(
    float* __restrict__ zT, float* __restrict__ hT,
    const float* __restrict__ mu, const float* __restrict__ c,
    const float* __restrict__ Wp, const float* __restrict__ bp,
    const float* __restrict__ Wr, const float* __restrict__ br,
    float* __restrict__ actT, float* __restrict__ postb,
    float* __restrict__ out, int t)
{
    __shared__ alignas(16) float mu_s[64];
    __shared__ alignas(16) float c_s[512];
    __shared__ alignas(16) float wp_s[512];
    __shared__ alignas(16) float bp_s[64];
    __shared__ alignas(16) float wr_s[704];   // [ch][11] padded: avoids 4-way conflict
    __shared__ alignas(16) float br_s[16];
    const int tid = threadIdx.x;
    if (tid < 64) { mu_s[tid] = mu[tid]; bp_s[tid] = bp[tid]; }
    for (int i = tid; i < 512; i += 256) { c_s[i] = c[i]; wp_s[i] = Wp[i]; }
    const bool last = (t == T_STEPS - 1);
    if (last) {
        for (int i = tid; i < 640; i += 256) wr_s[(i / 10) * 11 + (i % 10)] = Wr[i];
        if (tid < N_CLS) br_s[tid] = br[tid];
    }
    __syncthreads();

    const int sub  = tid & 7;
    const int b    = blockIdx.x * 32 + (tid >> 3);
    const int lane = tid & 63;
    const int gbase = lane & ~7;

    // load z (coalesced) then broadcast across the 8-lane group
    float zown = zT[(size_t)b * 8 + sub];
    float z[8];
    #pragma unroll
    for (int d = 0; d < 8; ++d) z[d] = __shfl(zown, gbase + d, 64);

    // PM evolve: 4 substeps; each lane sums 8 centers, butterfly-reduce force.
    #pragma unroll 1
    for (int it = 0; it < PM_STEPS; ++it) {
        float f[8];
        #pragma unroll
        for (int d = 0; d < 8; ++d) f[d] = 0.f;
        #pragma unroll
        for (int k = 0; k < 8; ++k) {
            const int n = sub + 8 * k;            // striped: conflict-free c_s banks
            float dx[8];
            float r2 = EPS_C;
            #pragma unroll
            for (int d = 0; d < 8; ++d) {
                dx[d] = c_s[n * 8 + d] - z[d];
                r2 = fmaf(dx[d], dx[d], r2);
            }
            float w = mu_s[n] / r2;
            #pragma unroll
            for (int d = 0; d < 8; ++d) f[d] = fmaf(w, dx[d], f[d]);
        }
        #pragma unroll
        for (int m = 1; m <= 4; m <<= 1)
            #pragma unroll
            for (int d = 0; d < 8; ++d) f[d] += __shfl_xor(f[d], m, 64);
        #pragma unroll
        for (int d = 0; d < 8; ++d) z[d] = fmaf(DT_C, f[d], z[d]);
    }
    // store z (lane sub writes element sub; static-select to avoid scratch)
    float zsel = z[0];
    #pragma unroll
    for (int d = 1; d < 8; ++d) if (sub == d) zsel = z[d];
    zT[(size_t)b * 8 + sub] = zsel;

    // membrane + EI: 8 channels per lane (ch = sub*8+j)
    float hn[8];
    float s = 0.f;
    #pragma unroll
    for (int j = 0; j < 8; ++j) {
        const int ch = sub * 8 + j;
        float a = bp_s[ch];
        #pragma unroll
        for (int d = 0; d < 8; ++d) a = fmaf(z[d], wp_s[d * 64 + ch], a);
        hn[j] = tanhf(a);
    }
    if (t == 0) {
        #pragma unroll
        for (int j = 0; j < 8; ++j) { hn[j] = MGAIN * hn[j]; s += hn[j]; }
    } else {
        const float4* hp = (const float4*)(hT + (size_t)b * 64 + sub * 8);
        float4 h0 = hp[0], h1v = hp[1];
        hn[0] = TAU_C * h0.x + MGAIN * hn[0];
        hn[1] = TAU_C * h0.y + MGAIN * hn[1];
        hn[2] = TAU_C * h0.z + MGAIN * hn[2];
        hn[3] = TAU_C * h0.w + MGAIN * hn[3];
        hn[4] = TAU_C * h1v.x + MGAIN * hn[4];
        hn[5] = TAU_C * h1v.y + MGAIN * hn[5];
        hn[6] = TAU_C * h1v.z + MGAIN * hn[6];
        hn[7] = TAU_C * h1v.w + MGAIN * hn[7];
        #pragma unroll
        for (int j = 0; j < 8; ++j) s += hn[j];
    }
    #pragma unroll
    for (int m = 1; m <= 4; m <<= 1) s += __shfl_xor(s, m, 64);
    const float mean = s * (1.f / 64.f);
    float spost = 0.f;
    #pragma unroll
    for (int j = 0; j < 8; ++j) {
        hn[j] = hn[j] + EIG * (hn[j] - mean);
        spost += hn[j];
    }
    {
        float4 a0 = {hn[0], hn[1], hn[2], hn[3]};
        float4 a1 = {hn[4], hn[5], hn[6], hn[7]};
        float4* hp = (float4*)(hT + (size_t)b * 64 + sub * 8);
        hp[0] = a0; hp[1] = a1;
    }
    #pragma unroll
    for (int m = 1; m <= 4; m <<= 1) spost += __shfl_xor(spost, m, 64);

    if (!last) {
        if (sub == 0) postb[b] = spost * (1.f / 64.f);
        #pragma unroll
        for (int k = 0; k < 8; ++k) {
            const int n = sub + 8 * k;
            float r2 = 0.f;
            #pragma unroll
            for (int d = 0; d < 8; ++d) {
                float dd = c_s[n * 8 + d] - z[d];
                r2 = fmaf(dd, dd, r2);
            }
            actT[(size_t)b * 64 + n] = expf(-r2);
        }
    } else {
        // logits: partial over this lane's 8 channels, butterfly, lane0 writes
        float lg[N_CLS];
        #pragma unroll
        for (int cls = 0; cls < N_CLS; ++cls) lg[cls] = 0.f;
        #pragma unroll
        for (int j = 0; j < 8; ++j) {
            const int ch = sub * 8 + j;
            #pragma unroll
            for (int cls = 0; cls < N_CLS; ++cls)
                lg[cls] = fmaf(hn[j], wr_s[ch * 11 + cls], lg[cls]);
        }
        #pragma unroll
        for (int m = 1; m <= 4; m <<= 1)
            #pragma unroll
            for (int cls = 0; cls < N_CLS; ++cls) lg[cls] += __shfl_xor(lg[cls], m, 64);
        if (sub == 0) {
            #pragma unroll
            for (int cls = 0; cls < N_CLS; ++cls)
                out[(size_t)b * 10 + cls] = lg[cls] + br_s[cls];
        }
        out[163840 + (size_t)b * 8 + sub] = zsel;
        {
            float4 a0 = {hn[0], hn[1], hn[2], hn[3]};
            float4 a1 = {hn[4], hn[5], hn[6], hn[7]};
            float4* op = (float4*)(out + 294912 + (size_t)b * 64 + sub * 8);
            op[0] = a0; op[1] = a1;
        }
    }
}

// ---------------- stepB stage 1: per-chunk partial sums ----------------
__global__ __launch_bounds__(256) void stepB1_kernel(
    const float* __restrict__ actT, const float* __restrict__ postb,
    const float* __restrict__ zT, float* __restrict__ part)
{
    const int g = blockIdx.x, tid = threadIdx.x;
    const int n = tid & 63, q = tid >> 6;
    const int b0 = g * 64 + q * 16;
    float acc[10];
    #pragma unroll
    for (int j = 0; j < 10; ++j) acc[j] = 0.f;
    for (int i = 0; i < 16; ++i) {
        const int b = b0 + i;
        float a = actT[(size_t)b * 64 + n];
        float p = postb[b];
        acc[0] += a;
        acc[1] = fmaf(a, p, acc[1]);
        #pragma unroll
        for (int d = 0; d < 8; ++d)
            acc[2 + d] = fmaf(a, zT[(size_t)b * 8 + d], acc[2 + d]);
    }
    __shared__ float red[4][64][10];
    #pragma unroll
    for (int j = 0; j < 10; ++j) red[q][n][j] = acc[j];
    __syncthreads();
    if (q == 0) {
        #pragma unroll
        for (int j = 0; j < 10; ++j) {
            float sv = (red[0][n][j] + red[1][n][j]) + (red[2][n][j] + red[3][n][j]);
            part[(size_t)(g * 64 + n) * 10 + j] = sv;
        }
    }
}

// ---------------- stepB stage 2: final reduce + mu/c update ----------------
__global__ __launch_bounds__(256) void stepB2_kernel(
    const float* __restrict__ part,
    const float* __restrict__ mu_in, const float* __restrict__ c_in,
    float* __restrict__ mu_out, float* __restrict__ c_out)
{
    const int n = blockIdx.x, tid = threadIdx.x;
    __shared__ float red[256][10];
    const float* p = part + ((size_t)tid * 64 + n) * 10;
    #pragma unroll
    for (int j = 0; j < 10; ++j) red[tid][j] = p[j];
    __syncthreads();
    for (int s = 128; s > 0; s >>= 1) {
        if (tid < s) {
            #pragma unroll
            for (int j = 0; j < 10; ++j) red[tid][j] += red[tid + s][j];
        }
        __syncthreads();
    }
    if (tid == 0) {
        const float S1 = red[0][0];
        const float S2 = red[0][1] * (1.f / B_N);
        mu_out[n] = mu_in[n] + PLR_C * S2;
        const float denom = S1 + EPS_C;
        #pragma unroll
        for (int d = 0; d < 8; ++d) {
            float s3 = red[0][2 + d];
            c_out[n * 8 + d] = c_in[n * 8 + d] + PLR_C * (s3 / denom - c_in[n * 8 + d] * (S1 / denom));
        }
    }
}

extern "C" void kernel_launch(void* const* d_in, const int* in_sizes, int n_in,
                              void* d_out, int out_size, void* d_ws, size_t ws_size,
                              hipStream_t stream) {
    (void)in_sizes; (void)n_in; (void)out_size; (void)ws_size;
    const float* x   = (const float*)d_in[0];
    const float* W1  = (const float*)d_in[1];
    const float* b1  = (const float*)d_in[2];
    const float* W2  = (const float*)d_in[3];
    const float* b2  = (const float*)d_in[4];
    const float* mu0 = (const float*)d_in[5];
    const float* c0  = (const float*)d_in[6];
    const float* Wp  = (const float*)d_in[7];
    const float* bp  = (const float*)d_in[8];
    const float* Wr  = (const float*)d_in[9];
    const float* br  = (const float*)d_in[10];
    float* out = (float*)d_out;
    float* ws  = (float*)d_ws;

    // ws layout (floats). h1 (16 MB) dead after enc2; hT/actT/postb/part alias it.
    float* h1    = ws;                       // [B,256]    4,194,304
    float* hT    = ws;                       // [B][64]    1,048,576 (aliases h1)
    float* actT  = ws + 1048576;             // [B][64]    1,048,576 (aliases h1)
    float* postb = ws + 2097152;             // [B]           16,384 (aliases h1)
    float* part  = ws + 2113536;             // [256][64][10] 163,840 (aliases h1)
    float* zT    = ws + 4194304;             // [B][8]       131,072
    float* mu_buf = ws + 4325376;            // 2 x 64
    float* c_buf  = ws + 4325504;            // 2 x 512

    enc1_kernel<<<dim3(4, 256), 256, 0, stream>>>(x, W1, b1, h1);
    enc2_kernel<<<512, 256, 0, stream>>>(h1, W2, b2, zT);

    const float* mu_cur = mu0;
    const float* c_cur  = c0;
    for (int t = 0; t < T_STEPS; ++t) {
        stepA2_kernel<<<512, 256, 0, stream>>>(zT, hT, mu_cur, c_cur, Wp, bp, Wr, br,
                                               actT, postb, out, t);
        if (t < T_STEPS - 1) {
            stepB1_kernel<<<256, 256, 0, stream>>>(actT, postb, zT, part);
            float* mo = mu_buf + (t & 1) * 64;
            float* co = c_buf  + (t & 1) * 512;
            stepB2_kernel<<<64, 256, 0, stream>>>(part, mu_cur, c_cur, mo, co);
            mu_cur = mo;
            c_cur  = co;
        }
    }
}